// Round 7
// baseline (59.794 us; speedup 1.0000x reference)
//
#include <hip/hip_runtime.h>
#include <math.h>

#define NN 50000
#define NE 800000
#define KD 256      // 2*D
#define DD 128
#define ROWS 32
#define NT ((NN + ROWS - 1) / ROWS)   // 1563

// SpMV privatization geometry
#define EC 64
#define NR 4
#define RNG 12500
#define QPC 3125

// workspace layout (floats)
#define S_OFF   0
#define P_OFF   50176
#define CNT_OFF (P_OFF + EC * NN)          // 3250176
#define W1P_OFF (CNT_OFF + 16)             // 3250192 (16B-aligned)
#define WS_NEED ((size_t)(W1P_OFF + DD * KD / 2 + 16) * 4)

typedef __bf16 bf16x4 __attribute__((ext_vector_type(4)));
typedef __bf16 bf16x8 __attribute__((ext_vector_type(8)));
typedef float f32x4 __attribute__((ext_vector_type(4)));

// Prep: W1 f32 [128][256] -> FRAGMENT-MAJOR bf16 (wave's B-frag for (d-tile,ks) is 1 KB contiguous)
__global__ void prep_w1_kernel(const float* __restrict__ W1, __bf16* __restrict__ W1p)
{
    int i = blockIdx.x * 256 + threadIdx.x;   // one per (d, ks, g): 128*8*4 = 4096
    if (i >= DD * 8 * 4) return;
    int g  = i & 3;
    int ks = (i >> 2) & 7;
    int d  = i >> 5;
    int dt = d >> 4, li = d & 15;
    const float* src = W1 + d * KD + ks * 32 + g * 8;
    float4 v0 = *(const float4*)(src);
    float4 v1 = *(const float4*)(src + 4);
    bf16x8 h = { (__bf16)v0.x, (__bf16)v0.y, (__bf16)v0.z, (__bf16)v0.w,
                 (__bf16)v1.x, (__bf16)v1.y, (__bf16)v1.z, (__bf16)v1.w };
    *(bf16x8*)&W1p[(size_t)(((dt * 8 + ks) * 64) + g * 16 + li) * 8] = h;
}

// Stage 1 (MFMA, barrier-free): A-frags loaded DIRECTLY from global x (in-register f32->bf16),
// B-frags streamed from frag-major W1p. No LDS staging, no hot-path __syncthreads:
// pure load->cvt->MFMA per wave, fully unrolled for max memory-level parallelism.
__global__ __launch_bounds__(256, 2) void stage1_kernel(
    const float* __restrict__ x, const __bf16* __restrict__ W1p,
    const float* __restrict__ b1, const float* __restrict__ W2,
    float* __restrict__ s, float* __restrict__ out, unsigned* __restrict__ counter)
{
    __shared__ float sred[4][ROWS];   // 512 B only

    const int tid  = threadIdx.x;
    const int lane = tid & 63;
    const int w    = tid >> 6;      // wave owns d-quarter [32w, 32w+32)
    const int g    = lane >> 4;     // k-group
    const int li   = lane & 15;     // row/col within 16
    const int m0   = blockIdx.x * ROWS;

    if (blockIdx.x == 0 && tid == 0) { out[0] = 0.f; counter[0] = 0u; }

    // A row bases (clamped for the tail tile; dup rows are masked at the final store)
    int r0 = m0 + li;      r0 = r0 < NN ? r0 : NN - 1;
    int r1 = m0 + 16 + li; r1 = r1 < NN ? r1 : NN - 1;
    const float* xb0 = x + (size_t)r0 * KD + g * 8;
    const float* xb1 = x + (size_t)r1 * KD + g * 8;
    // B frag bases (frag-major): wave w owns d-tiles 2w, 2w+1
    const __bf16* fb0 = W1p + ((size_t)((2 * w)     * 8) * 64 + lane) * 8;
    const __bf16* fb1 = W1p + ((size_t)((2 * w + 1) * 8) * 64 + lane) * 8;

    const int d0 = w * 32 + li;
    const float b1v0 = b1[d0], b1v1 = b1[d0 + 16];
    const float w2v0 = W2[d0], w2v1 = W2[d0 + 16];

    // K-loop: k = ks*32 + g*8 + j for both A and B (same bijection -> HW k-order independent)
    f32x4 acc[2][2] = {};
    #pragma unroll
    for (int ks = 0; ks < 8; ++ks) {
        float4 a0l = *(const float4*)(xb0 + ks * 32);
        float4 a0h = *(const float4*)(xb0 + ks * 32 + 4);
        float4 a1l = *(const float4*)(xb1 + ks * 32);
        float4 a1h = *(const float4*)(xb1 + ks * 32 + 4);
        bf16x8 b0  = *(const bf16x8*)(fb0 + (size_t)ks * 512);
        bf16x8 b1f = *(const bf16x8*)(fb1 + (size_t)ks * 512);
        bf16x8 a0 = { (__bf16)a0l.x, (__bf16)a0l.y, (__bf16)a0l.z, (__bf16)a0l.w,
                      (__bf16)a0h.x, (__bf16)a0h.y, (__bf16)a0h.z, (__bf16)a0h.w };
        bf16x8 a1 = { (__bf16)a1l.x, (__bf16)a1l.y, (__bf16)a1l.z, (__bf16)a1l.w,
                      (__bf16)a1h.x, (__bf16)a1h.y, (__bf16)a1h.z, (__bf16)a1h.w };
        acc[0][0] = __builtin_amdgcn_mfma_f32_16x16x32_bf16(a0, b0,  acc[0][0], 0, 0, 0);
        acc[0][1] = __builtin_amdgcn_mfma_f32_16x16x32_bf16(a0, b1f, acc[0][1], 0, 0, 0);
        acc[1][0] = __builtin_amdgcn_mfma_f32_16x16x32_bf16(a1, b0,  acc[1][0], 0, 0, 0);
        acc[1][1] = __builtin_amdgcn_mfma_f32_16x16x32_bf16(a1, b1f, acc[1][1], 0, 0, 0);
    }

    // Epilogue: v = sin(acc+b1)*W2, reduce over d (C/D: col=lane&15, row=(lane>>4)*4+reg)
    #pragma unroll
    for (int mt = 0; mt < 2; ++mt) {
        #pragma unroll
        for (int r = 0; r < 4; ++r) {
            float v = __sinf(acc[mt][0][r] + b1v0) * w2v0
                    + __sinf(acc[mt][1][r] + b1v1) * w2v1;
            v += __shfl_xor(v, 1); v += __shfl_xor(v, 2);
            v += __shfl_xor(v, 4); v += __shfl_xor(v, 8);
            if (li == 0) sred[w][mt * 16 + g * 4 + r] = v;
        }
    }
    __syncthreads();   // only barrier: 512 B sred handoff
    if (tid < ROWS) {
        int m = m0 + tid;
        if (m < NN) s[m] = sred[0][tid] + sred[1][tid] + sred[2][tid] + sred[3][tid];
    }
}

// Stage 2 (LDS-privatized, no device atomics): block (nr, ecid) scans chunk ecid,
// accumulates rows in its range into LDS, writes partial range to P[ecid][...].
__global__ __launch_bounds__(1024, 1) void spmv_lds_kernel(
    const int* __restrict__ erow, const int* __restrict__ ecol,
    const float* __restrict__ ew, const float* __restrict__ s,
    float* __restrict__ P)
{
    __shared__ float lt[RNG];
    const int tid  = threadIdx.x;
    const int ecid = blockIdx.x & 63;
    const int nr   = blockIdx.x >> 6;
    const int base = nr * RNG;

    for (int i = tid; i < RNG; i += 1024) lt[i] = 0.f;
    __syncthreads();

    const int4*   r4p = (const int4*)erow;
    const int4*   c4p = (const int4*)ecol;
    const float4* w4p = (const float4*)ew;
    for (int q = tid; q < QPC; q += 1024) {
        int i = ecid * QPC + q;
        int4   r4 = r4p[i];
        int4   c4 = c4p[i];
        float4 w4 = w4p[i];
        unsigned a;
        a = (unsigned)(r4.x - base); if (a < RNG) atomicAdd(&lt[a], w4.x * s[c4.x]);
        a = (unsigned)(r4.y - base); if (a < RNG) atomicAdd(&lt[a], w4.y * s[c4.y]);
        a = (unsigned)(r4.z - base); if (a < RNG) atomicAdd(&lt[a], w4.z * s[c4.z]);
        a = (unsigned)(r4.w - base); if (a < RNG) atomicAdd(&lt[a], w4.w * s[c4.w]);
    }
    __syncthreads();

    float4*       dst = (float4*)(P + (size_t)ecid * NN + base);
    const float4* src = (const float4*)lt;
    for (int j = tid; j < RNG / 4; j += 1024) dst[j] = src[j];
}

// Stage 3: out += sum_n sin(sum_ec P[ec][n] + b2)^2 ; last block applies sqrt.
__global__ void finish_lds_kernel(const float* __restrict__ P, const float* __restrict__ b2,
                                  float* __restrict__ out, unsigned* __restrict__ counter,
                                  int nblocks)
{
    int n = blockIdx.x * 256 + threadIdx.x;
    float v = 0.f;
    if (n < NN) {
        float a = 0.f;
        #pragma unroll 8
        for (int ec = 0; ec < EC; ++ec) a += P[(size_t)ec * NN + n];
        float o = __sinf(a + b2[0]);
        v = o * o;
    }
    #pragma unroll
    for (int off = 32; off; off >>= 1) v += __shfl_xor(v, off);
    __shared__ float partial[4];
    if ((threadIdx.x & 63) == 0) partial[threadIdx.x >> 6] = v;
    __syncthreads();
    if (threadIdx.x == 0) {
        atomicAdd(out, partial[0] + partial[1] + partial[2] + partial[3]);
        __threadfence();
        unsigned old = atomicAdd(counter, 1u);
        if (old == (unsigned)(nblocks - 1)) {
            float tot = atomicAdd(out, 0.f);   // atomic read: all prior adds visible
            out[0] = sqrtf(tot);
        }
    }
}

// ---- Fallback path (small workspace): dense atomic SpMV ----
__global__ void spmv_fallback_kernel(const int* __restrict__ erow, const int* __restrict__ ecol,
                                     const float* __restrict__ ew, const float* __restrict__ s,
                                     float* __restrict__ t)
{
    int i = blockIdx.x * 256 + threadIdx.x;
    if (i >= NE / 4) return;
    int4   r4 = ((const int4*)erow)[i];
    int4   c4 = ((const int4*)ecol)[i];
    float4 w4 = ((const float4*)ew)[i];
    atomicAdd(&t[r4.x], w4.x * s[c4.x]);
    atomicAdd(&t[r4.y], w4.y * s[c4.y]);
    atomicAdd(&t[r4.z], w4.z * s[c4.z]);
    atomicAdd(&t[r4.w], w4.w * s[c4.w]);
}

__global__ void finish_fallback_kernel(const float* __restrict__ t, const float* __restrict__ b2,
                                       float* __restrict__ out)
{
    int n = blockIdx.x * 256 + threadIdx.x;
    float v = 0.f;
    if (n < NN) { float o = __sinf(t[n] + b2[0]); v = o * o; }
    #pragma unroll
    for (int off = 32; off; off >>= 1) v += __shfl_xor(v, off);
    __shared__ float partial[4];
    if ((threadIdx.x & 63) == 0) partial[threadIdx.x >> 6] = v;
    __syncthreads();
    if (threadIdx.x == 0)
        atomicAdd(out, partial[0] + partial[1] + partial[2] + partial[3]);
}

__global__ void sqrt_kernel(float* out) { out[0] = sqrtf(out[0]); }

__global__ void zero_kernel(float* t, float* out)
{
    int i = blockIdx.x * 256 + threadIdx.x;
    if (i < NN) t[i] = 0.f;
    if (i == 0) out[0] = 0.f;
}

extern "C" void kernel_launch(void* const* d_in, const int* in_sizes, int n_in,
                              void* d_out, int out_size, void* d_ws, size_t ws_size,
                              hipStream_t stream)
{
    const float* x   = (const float*)d_in[0];
    const float* W1  = (const float*)d_in[1];
    const float* b1  = (const float*)d_in[2];
    const float* W2  = (const float*)d_in[3];
    const float* b2  = (const float*)d_in[4];
    const int*   er  = (const int*)d_in[5];
    const int*   ec  = ((const int*)d_in[5]) + NE;
    const float* ew  = (const float*)d_in[6];
    float* out = (float*)d_out;

    float*    ws    = (float*)d_ws;
    float*    s_buf = ws + S_OFF;
    float*    P     = ws + P_OFF;
    unsigned* cnt   = (unsigned*)(ws + CNT_OFF);
    __bf16*   W1p   = (__bf16*)(ws + W1P_OFF);

    if (ws_size >= WS_NEED) {
        prep_w1_kernel<<<16, 256, 0, stream>>>(W1, W1p);
        stage1_kernel<<<NT, 256, 0, stream>>>(x, W1p, b1, W2, s_buf, out, cnt);
        spmv_lds_kernel<<<NR * EC, 1024, 0, stream>>>(er, ec, ew, s_buf, P);
        int fb = (NN + 255) / 256;
        finish_lds_kernel<<<fb, 256, 0, stream>>>(P, b2, out, cnt, fb);
    } else {
        // Dense-atomic fallback (needs only ~400 KB of ws)
        __bf16*   W1pf = (__bf16*)(ws + 50176 + NN);
        unsigned* cntf = (unsigned*)(ws + 50176 + NN + DD * KD / 2);
        prep_w1_kernel<<<16, 256, 0, stream>>>(W1, W1pf);
        zero_kernel<<<(NN + 255) / 256, 256, 0, stream>>>(ws + 50176, out);
        stage1_kernel<<<NT, 256, 0, stream>>>(x, W1pf, b1, W2, s_buf, out, cntf);
        spmv_fallback_kernel<<<(NE / 4 + 255) / 256, 256, 0, stream>>>(er, ec, ew, s_buf, ws + 50176);
        finish_fallback_kernel<<<(NN + 255) / 256, 256, 0, stream>>>(ws + 50176, b2, out);
        sqrt_kernel<<<1, 1, 0, stream>>>(out);
    }
}

// Round 8
// 49.034 us; speedup vs baseline: 1.2194x; 1.2194x over previous
//
#include <hip/hip_runtime.h>
#include <math.h>

#define NN 50000
#define NE 800000
#define KD 256      // 2*D
#define DD 128
#define ROWS 16     // rows per tile (50000 = 3125 * 16, exact)
#define STR 264     // padded LDS row stride (bf16 elems)
#define NTILE 3125

// SpMV privatization geometry
#define EC 64
#define NR 4
#define RNG 12500
#define QPC 3125

// workspace layout (floats)
#define SA_OFF  0
#define SB_OFF  50176
#define P_OFF   100352
#define CNT_OFF (P_OFF + EC * NN)          // 3300352
#define W1P_OFF (CNT_OFF + 16)
#define WS_NEED ((size_t)(W1P_OFF + DD * KD / 2 + 16) * 4)

typedef __bf16 bf16x4 __attribute__((ext_vector_type(4)));
typedef __bf16 bf16x8 __attribute__((ext_vector_type(8)));
typedef float f32x4 __attribute__((ext_vector_type(4)));

// Prep: W1 f32 [128][256] -> FRAGMENT-MAJOR bf16; also zero out/counter.
// W1p[((dt*8+ks)*64 + g*16+li)*8 + j] = W1[(dt*16+li)*256 + ks*32 + g*8 + j]
__global__ void prep_w1_kernel(const float* __restrict__ W1, __bf16* __restrict__ W1p,
                               float* __restrict__ out, unsigned* __restrict__ counter)
{
    int i = blockIdx.x * 256 + threadIdx.x;   // one per (d, ks, g): 128*8*4 = 4096
    if (i == 0) { out[0] = 0.f; counter[0] = 0u; }
    if (i >= DD * 8 * 4) return;
    int g  = i & 3;
    int ks = (i >> 2) & 7;
    int d  = i >> 5;
    int dt = d >> 4, li = d & 15;
    const float* src = W1 + d * KD + ks * 32 + g * 8;
    float4 v0 = *(const float4*)(src);
    float4 v1 = *(const float4*)(src + 4);
    bf16x8 h = { (__bf16)v0.x, (__bf16)v0.y, (__bf16)v0.z, (__bf16)v0.w,
                 (__bf16)v1.x, (__bf16)v1.y, (__bf16)v1.z, (__bf16)v1.w };
    *(bf16x8*)&W1p[(size_t)(((dt * 8 + ks) * 64) + g * 16 + li) * 8] = h;
}

// Stage 1 (MFMA, hi-occupancy split-d): block = (tile, d-half); 16-row tile; wave owns ONE
// 16-d tile with all 8 B-frags register-resident (frag-major W1p, coalesced). 20 waves/CU.
__global__ __launch_bounds__(256, 5) void stage1_kernel(
    const float* __restrict__ x, const __bf16* __restrict__ W1p,
    const float* __restrict__ b1, const float* __restrict__ W2,
    float* __restrict__ s_base)
{
    __shared__ __align__(16) __bf16 xs[ROWS * STR];   // 8448 B
    __shared__ float sred[4][ROWS];

    const int tid  = threadIdx.x;
    const int lane = tid & 63;
    const int w    = tid >> 6;
    const int g    = lane >> 4;
    const int li   = lane & 15;
    const int tile = blockIdx.x >> 1;
    const int half = blockIdx.x & 1;
    const int m0   = tile * ROWS;
    const int dt   = half * 4 + w;       // this wave's d-tile (0..7)

    // x tile loads: 16 rows x 256 f32 = 1024 float4, 4 per thread, coalesced. No tail (exact).
    float4 xr[4];
    #pragma unroll
    for (int i = 0; i < 4; ++i) {
        int c = tid + i * 256;
        int r = c >> 6, kq = c & 63;
        xr[i] = ((const float4*)x)[(size_t)(m0 + r) * 64 + kq];
    }

    // All 8 B-frags into registers (each: wave reads contiguous 1 KB from L2-hot W1p).
    const __bf16* fb = W1p + ((size_t)(dt * 8) * 64 + lane) * 8;
    bf16x8 bw[8];
    #pragma unroll
    for (int ks = 0; ks < 8; ++ks)
        bw[ks] = *(const bf16x8*)(fb + (size_t)ks * 512);

    const int d0 = dt * 16 + li;
    const float b1v = b1[d0];
    const float w2v = W2[d0];

    // Convert + stage x tile to LDS
    #pragma unroll
    for (int i = 0; i < 4; ++i) {
        int c = tid + i * 256;
        int r = c >> 6, kq = c & 63;
        bf16x4 h = { (__bf16)xr[i].x, (__bf16)xr[i].y, (__bf16)xr[i].z, (__bf16)xr[i].w };
        *(bf16x4*)&xs[r * STR + kq * 4] = h;
    }
    __syncthreads();

    // K-loop: A from LDS (uniform-bank b128), B from regs. k = ks*32+g*8+j both sides.
    f32x4 acc = {};
    #pragma unroll
    for (int ks = 0; ks < 8; ++ks) {
        bf16x8 a = *(const bf16x8*)&xs[li * STR + ks * 32 + g * 8];
        acc = __builtin_amdgcn_mfma_f32_16x16x32_bf16(a, bw[ks], acc, 0, 0, 0);
    }

    // Epilogue: v = sin(acc+b1)*W2, reduce over d-lanes (C/D: col=li, row=g*4+r)
    #pragma unroll
    for (int r = 0; r < 4; ++r) {
        float v = __sinf(acc[r] + b1v) * w2v;
        v += __shfl_xor(v, 1); v += __shfl_xor(v, 2);
        v += __shfl_xor(v, 4); v += __shfl_xor(v, 8);
        if (li == 0) sred[w][g * 4 + r] = v;
    }
    __syncthreads();
    if (tid < ROWS)
        s_base[half * SB_OFF + m0 + tid] =
            sred[0][tid] + sred[1][tid] + sred[2][tid] + sred[3][tid];
}

// Stage 2 (LDS-privatized): block (nr, ecid) scans chunk ecid, accumulates its node range
// in LDS, writes partial range to P[ecid][...]. s = sA + sB (both L2-resident).
__global__ __launch_bounds__(1024, 1) void spmv_lds_kernel(
    const int* __restrict__ erow, const int* __restrict__ ecol,
    const float* __restrict__ ew, const float* __restrict__ sA,
    const float* __restrict__ sB, float* __restrict__ P)
{
    __shared__ float lt[RNG];
    const int tid  = threadIdx.x;
    const int ecid = blockIdx.x & 63;
    const int nr   = blockIdx.x >> 6;
    const int base = nr * RNG;

    for (int i = tid; i < RNG; i += 1024) lt[i] = 0.f;
    __syncthreads();

    const int4*   r4p = (const int4*)erow;
    const int4*   c4p = (const int4*)ecol;
    const float4* w4p = (const float4*)ew;
    for (int q = tid; q < QPC; q += 1024) {
        int i = ecid * QPC + q;
        int4   r4 = r4p[i];
        int4   c4 = c4p[i];
        float4 w4 = w4p[i];
        unsigned a;
        a = (unsigned)(r4.x - base); if (a < RNG) atomicAdd(&lt[a], w4.x * (sA[c4.x] + sB[c4.x]));
        a = (unsigned)(r4.y - base); if (a < RNG) atomicAdd(&lt[a], w4.y * (sA[c4.y] + sB[c4.y]));
        a = (unsigned)(r4.z - base); if (a < RNG) atomicAdd(&lt[a], w4.z * (sA[c4.z] + sB[c4.z]));
        a = (unsigned)(r4.w - base); if (a < RNG) atomicAdd(&lt[a], w4.w * (sA[c4.w] + sB[c4.w]));
    }
    __syncthreads();

    float4*       dst = (float4*)(P + (size_t)ecid * NN + base);
    const float4* src = (const float4*)lt;
    for (int j = tid; j < RNG / 4; j += 1024) dst[j] = src[j];
}

// Stage 3: out += sum_n sin(sum_ec P[ec][n] + b2)^2 ; last block applies sqrt.
__global__ void finish_lds_kernel(const float* __restrict__ P, const float* __restrict__ b2,
                                  float* __restrict__ out, unsigned* __restrict__ counter,
                                  int nblocks)
{
    int n = blockIdx.x * 256 + threadIdx.x;
    float v = 0.f;
    if (n < NN) {
        float a = 0.f;
        #pragma unroll 8
        for (int ec = 0; ec < EC; ++ec) a += P[(size_t)ec * NN + n];
        float o = __sinf(a + b2[0]);
        v = o * o;
    }
    #pragma unroll
    for (int off = 32; off; off >>= 1) v += __shfl_xor(v, off);
    __shared__ float partial[4];
    if ((threadIdx.x & 63) == 0) partial[threadIdx.x >> 6] = v;
    __syncthreads();
    if (threadIdx.x == 0) {
        atomicAdd(out, partial[0] + partial[1] + partial[2] + partial[3]);
        __threadfence();
        unsigned old = atomicAdd(counter, 1u);
        if (old == (unsigned)(nblocks - 1)) {
            float tot = atomicAdd(out, 0.f);   // atomic read: all prior adds visible
            out[0] = sqrtf(tot);
        }
    }
}

// ---- Fallback path (small workspace): dense atomic SpMV ----
__global__ void spmv_fallback_kernel(const int* __restrict__ erow, const int* __restrict__ ecol,
                                     const float* __restrict__ ew, const float* __restrict__ sA,
                                     const float* __restrict__ sB, float* __restrict__ t)
{
    int i = blockIdx.x * 256 + threadIdx.x;
    if (i >= NE / 4) return;
    int4   r4 = ((const int4*)erow)[i];
    int4   c4 = ((const int4*)ecol)[i];
    float4 w4 = ((const float4*)ew)[i];
    atomicAdd(&t[r4.x], w4.x * (sA[c4.x] + sB[c4.x]));
    atomicAdd(&t[r4.y], w4.y * (sA[c4.y] + sB[c4.y]));
    atomicAdd(&t[r4.z], w4.z * (sA[c4.z] + sB[c4.z]));
    atomicAdd(&t[r4.w], w4.w * (sA[c4.w] + sB[c4.w]));
}

__global__ void finish_fallback_kernel(const float* __restrict__ t, const float* __restrict__ b2,
                                       float* __restrict__ out)
{
    int n = blockIdx.x * 256 + threadIdx.x;
    float v = 0.f;
    if (n < NN) { float o = __sinf(t[n] + b2[0]); v = o * o; }
    #pragma unroll
    for (int off = 32; off; off >>= 1) v += __shfl_xor(v, off);
    __shared__ float partial[4];
    if ((threadIdx.x & 63) == 0) partial[threadIdx.x >> 6] = v;
    __syncthreads();
    if (threadIdx.x == 0)
        atomicAdd(out, partial[0] + partial[1] + partial[2] + partial[3]);
}

__global__ void sqrt_kernel(float* out) { out[0] = sqrtf(out[0]); }

__global__ void zero_kernel(float* t, float* out)
{
    int i = blockIdx.x * 256 + threadIdx.x;
    if (i < NN) t[i] = 0.f;
    if (i == 0) out[0] = 0.f;
}

extern "C" void kernel_launch(void* const* d_in, const int* in_sizes, int n_in,
                              void* d_out, int out_size, void* d_ws, size_t ws_size,
                              hipStream_t stream)
{
    const float* x   = (const float*)d_in[0];
    const float* W1  = (const float*)d_in[1];
    const float* b1  = (const float*)d_in[2];
    const float* W2  = (const float*)d_in[3];
    const float* b2  = (const float*)d_in[4];
    const int*   er  = (const int*)d_in[5];
    const int*   ec  = ((const int*)d_in[5]) + NE;
    const float* ew  = (const float*)d_in[6];
    float* out = (float*)d_out;

    float*    ws    = (float*)d_ws;
    float*    sA    = ws + SA_OFF;
    float*    sB    = ws + SB_OFF;
    float*    P     = ws + P_OFF;
    unsigned* cnt   = (unsigned*)(ws + CNT_OFF);
    __bf16*   W1p   = (__bf16*)(ws + W1P_OFF);

    if (ws_size >= WS_NEED) {
        prep_w1_kernel<<<16, 256, 0, stream>>>(W1, W1p, out, cnt);
        stage1_kernel<<<NTILE * 2, 256, 0, stream>>>(x, W1p, b1, W2, sA);
        spmv_lds_kernel<<<NR * EC, 1024, 0, stream>>>(er, ec, ew, sA, sB, P);
        int fb = (NN + 255) / 256;
        finish_lds_kernel<<<fb, 256, 0, stream>>>(P, b2, out, cnt, fb);
    } else {
        // Dense-atomic fallback (needs ~700 KB of ws)
        float*    t    = ws + P_OFF;
        __bf16*   W1pf = (__bf16*)(ws + P_OFF + NN);
        unsigned* cntf = (unsigned*)(ws + P_OFF + NN + DD * KD / 2);
        prep_w1_kernel<<<16, 256, 0, stream>>>(W1, W1pf, out, cntf);
        zero_kernel<<<(NN + 255) / 256, 256, 0, stream>>>(t, out);
        stage1_kernel<<<NTILE * 2, 256, 0, stream>>>(x, W1pf, b1, W2, sA);
        spmv_fallback_kernel<<<(NE / 4 + 255) / 256, 256, 0, stream>>>(er, ec, ew, sA, sB, t);
        finish_fallback_kernel<<<(NN + 255) / 256, 256, 0, stream>>>(t, b2, out);
        sqrt_kernel<<<1, 1, 0, stream>>>(out);
    }
}

// Round 9
// 42.637 us; speedup vs baseline: 1.4024x; 1.1500x over previous
//
#include <hip/hip_runtime.h>
#include <math.h>

#define NN 50000
#define NE 800000
#define KD 256      // 2*D
#define DD 128
#define ROWS 16     // rows per tile (50000 = 3125 * 16, exact)
#define NTILE 3125

// SpMV privatization geometry
#define EC 64
#define NR 4
#define RNG 12500
#define QPC 3125

// workspace layout (floats)
#define S_OFF   0
#define P_OFF   50176
#define CNT_OFF (P_OFF + EC * NN)
#define W1P_OFF (CNT_OFF + 16)
#define WS_NEED ((size_t)(W1P_OFF + DD * KD / 2 + 16) * 4)

typedef __bf16 bf16x4 __attribute__((ext_vector_type(4)));
typedef __bf16 bf16x8 __attribute__((ext_vector_type(8)));
typedef float f32x4 __attribute__((ext_vector_type(4)));

// Prep: W1 f32 [128][256] -> FRAGMENT-MAJOR bf16; also zero out/counter.
// W1p[((dt*8+ks)*64 + g*16+li)*8 + j] = W1[(dt*16+li)*256 + ks*32 + g*8 + j]
__global__ void prep_w1_kernel(const float* __restrict__ W1, __bf16* __restrict__ W1p,
                               float* __restrict__ out, unsigned* __restrict__ counter)
{
    int i = blockIdx.x * 256 + threadIdx.x;   // one per (d, ks, g): 128*8*4 = 4096
    if (i == 0) { out[0] = 0.f; counter[0] = 0u; }
    if (i >= DD * 8 * 4) return;
    int g  = i & 3;
    int ks = (i >> 2) & 7;
    int d  = i >> 5;
    int dt = d >> 4, li = d & 15;
    const float* src = W1 + d * KD + ks * 32 + g * 8;
    float4 v0 = *(const float4*)(src);
    float4 v1 = *(const float4*)(src + 4);
    bf16x8 h = { (__bf16)v0.x, (__bf16)v0.y, (__bf16)v0.z, (__bf16)v0.w,
                 (__bf16)v1.x, (__bf16)v1.y, (__bf16)v1.z, (__bf16)v1.w };
    *(bf16x8*)&W1p[(size_t)(((dt * 8 + ks) * 64) + g * 16 + li) * 8] = h;
}

// Stage 1 (MFMA, full occupancy): 16-row tile/block, full d=128 (x read once).
// x staged f32 -> LDS via global_load_lds (no staging VGPRs), with pre-swizzled
// global source + XOR-swizzled ds_read (G21 both-sides involution). f32->bf16 at
// read time. B-frags streamed from frag-major W1p (L2-hot). 8 blocks/CU target.
__global__ __launch_bounds__(256, 8) void stage1_kernel(
    const float* __restrict__ x, const __bf16* __restrict__ W1p,
    const float* __restrict__ b1, const float* __restrict__ W2,
    float* __restrict__ s)
{
    __shared__ __align__(16) float xs[ROWS * KD];   // 16 KB, linear (swizzled content)
    __shared__ float sred[4][ROWS];

    const int tid  = threadIdx.x;
    const int lane = tid & 63;
    const int w    = tid >> 6;
    const int g    = lane >> 4;
    const int li   = lane & 15;
    const int m0   = blockIdx.x * ROWS;

    // Async stage: each wave issues 4 rows; lane writes 16B linear at base+lane*16.
    // Source col pre-swizzled so LDS slot col' holds orig col = col' ^ ((row&7)<<2).
    #pragma unroll
    for (int i = 0; i < 4; ++i) {
        const int row = w * 4 + i;
        const int col = (4 * lane) ^ ((row & 7) << 2);
        __builtin_amdgcn_global_load_lds(
            (const __attribute__((address_space(1))) void*)(x + (size_t)(m0 + row) * KD + col),
            (__attribute__((address_space(3))) void*)&xs[row * KD], 16, 0, 0);
    }

    // B frag bases (frag-major): wave w owns d-tiles 2w, 2w+1. Prefetch ks=0.
    const __bf16* fb0 = W1p + ((size_t)((2 * w)     * 8) * 64 + lane) * 8;
    const __bf16* fb1 = W1p + ((size_t)((2 * w + 1) * 8) * 64 + lane) * 8;
    bf16x8 nb0 = *(const bf16x8*)fb0;
    bf16x8 nb1 = *(const bf16x8*)fb1;

    const int d0 = w * 32 + li;
    const float b1v0 = b1[d0], b1v1 = b1[d0 + 16];
    const float w2v0 = W2[d0], w2v1 = W2[d0 + 16];

    __syncthreads();   // drains vmcnt: x tile + B ks=0 resident

    // K-loop: A read swizzled from LDS f32 (2x b128, bank-floor), cvt to bf16,
    // B streamed 1-ahead. k = ks*32 + g*8 + j on both sides (same bijection).
    f32x4 acc0 = {}, acc1 = {};
    const int sw = (li & 7) << 2;
    #pragma unroll
    for (int ks = 0; ks < 8; ++ks) {
        bf16x8 cb0 = nb0, cb1 = nb1;
        if (ks < 7) {
            nb0 = *(const bf16x8*)(fb0 + (size_t)(ks + 1) * 512);
            nb1 = *(const bf16x8*)(fb1 + (size_t)(ks + 1) * 512);
        }
        const int cbase = ks * 32 + g * 8;
        float4 alo = *(const float4*)&xs[li * KD + ((cbase)     ^ sw)];
        float4 ahi = *(const float4*)&xs[li * KD + ((cbase + 4) ^ sw)];
        bf16x8 a = { (__bf16)alo.x, (__bf16)alo.y, (__bf16)alo.z, (__bf16)alo.w,
                     (__bf16)ahi.x, (__bf16)ahi.y, (__bf16)ahi.z, (__bf16)ahi.w };
        acc0 = __builtin_amdgcn_mfma_f32_16x16x32_bf16(a, cb0, acc0, 0, 0, 0);
        acc1 = __builtin_amdgcn_mfma_f32_16x16x32_bf16(a, cb1, acc1, 0, 0, 0);
    }

    // Epilogue: v = sin(acc+b1)*W2 summed over this wave's 32 d's, reduce over li.
    // C/D layout: col(d)=li, row(m)=g*4+r.
    #pragma unroll
    for (int r = 0; r < 4; ++r) {
        float v = __sinf(acc0[r] + b1v0) * w2v0 + __sinf(acc1[r] + b1v1) * w2v1;
        v += __shfl_xor(v, 1); v += __shfl_xor(v, 2);
        v += __shfl_xor(v, 4); v += __shfl_xor(v, 8);
        if (li == 0) sred[w][g * 4 + r] = v;
    }
    __syncthreads();
    if (tid < ROWS)
        s[m0 + tid] = sred[0][tid] + sred[1][tid] + sred[2][tid] + sred[3][tid];
}

// Stage 2 (LDS-privatized): block (nr, ecid) scans chunk ecid, accumulates its node
// range in LDS, writes partial range to P[ecid][...]. No device-scope atomics.
__global__ __launch_bounds__(1024, 1) void spmv_lds_kernel(
    const int* __restrict__ erow, const int* __restrict__ ecol,
    const float* __restrict__ ew, const float* __restrict__ s,
    float* __restrict__ P)
{
    __shared__ float lt[RNG];
    const int tid  = threadIdx.x;
    const int ecid = blockIdx.x & 63;
    const int nr   = blockIdx.x >> 6;
    const int base = nr * RNG;

    for (int i = tid; i < RNG; i += 1024) lt[i] = 0.f;
    __syncthreads();

    const int4*   r4p = (const int4*)erow;
    const int4*   c4p = (const int4*)ecol;
    const float4* w4p = (const float4*)ew;
    for (int q = tid; q < QPC; q += 1024) {
        int i = ecid * QPC + q;
        int4   r4 = r4p[i];
        int4   c4 = c4p[i];
        float4 w4 = w4p[i];
        unsigned a;
        a = (unsigned)(r4.x - base); if (a < RNG) atomicAdd(&lt[a], w4.x * s[c4.x]);
        a = (unsigned)(r4.y - base); if (a < RNG) atomicAdd(&lt[a], w4.y * s[c4.y]);
        a = (unsigned)(r4.z - base); if (a < RNG) atomicAdd(&lt[a], w4.z * s[c4.z]);
        a = (unsigned)(r4.w - base); if (a < RNG) atomicAdd(&lt[a], w4.w * s[c4.w]);
    }
    __syncthreads();

    float4*       dst = (float4*)(P + (size_t)ecid * NN + base);
    const float4* src = (const float4*)lt;
    for (int j = tid; j < RNG / 4; j += 1024) dst[j] = src[j];
}

// Stage 3: out += sum_n sin(sum_ec P[ec][n] + b2)^2 ; last block applies sqrt.
__global__ void finish_lds_kernel(const float* __restrict__ P, const float* __restrict__ b2,
                                  float* __restrict__ out, unsigned* __restrict__ counter,
                                  int nblocks)
{
    int n = blockIdx.x * 256 + threadIdx.x;
    float v = 0.f;
    if (n < NN) {
        float a = 0.f;
        #pragma unroll 8
        for (int ec = 0; ec < EC; ++ec) a += P[(size_t)ec * NN + n];
        float o = __sinf(a + b2[0]);
        v = o * o;
    }
    #pragma unroll
    for (int off = 32; off; off >>= 1) v += __shfl_xor(v, off);
    __shared__ float partial[4];
    if ((threadIdx.x & 63) == 0) partial[threadIdx.x >> 6] = v;
    __syncthreads();
    if (threadIdx.x == 0) {
        atomicAdd(out, partial[0] + partial[1] + partial[2] + partial[3]);
        __threadfence();
        unsigned old = atomicAdd(counter, 1u);
        if (old == (unsigned)(nblocks - 1)) {
            float tot = atomicAdd(out, 0.f);   // atomic read: all prior adds visible
            out[0] = sqrtf(tot);
        }
    }
}

// ---- Fallback path (small workspace): dense atomic SpMV ----
__global__ void spmv_fallback_kernel(const int* __restrict__ erow, const int* __restrict__ ecol,
                                     const float* __restrict__ ew, const float* __restrict__ s,
                                     float* __restrict__ t)
{
    int i = blockIdx.x * 256 + threadIdx.x;
    if (i >= NE / 4) return;
    int4   r4 = ((const int4*)erow)[i];
    int4   c4 = ((const int4*)ecol)[i];
    float4 w4 = ((const float4*)ew)[i];
    atomicAdd(&t[r4.x], w4.x * s[c4.x]);
    atomicAdd(&t[r4.y], w4.y * s[c4.y]);
    atomicAdd(&t[r4.z], w4.z * s[c4.z]);
    atomicAdd(&t[r4.w], w4.w * s[c4.w]);
}

__global__ void finish_fallback_kernel(const float* __restrict__ t, const float* __restrict__ b2,
                                       float* __restrict__ out)
{
    int n = blockIdx.x * 256 + threadIdx.x;
    float v = 0.f;
    if (n < NN) { float o = __sinf(t[n] + b2[0]); v = o * o; }
    #pragma unroll
    for (int off = 32; off; off >>= 1) v += __shfl_xor(v, off);
    __shared__ float partial[4];
    if ((threadIdx.x & 63) == 0) partial[threadIdx.x >> 6] = v;
    __syncthreads();
    if (threadIdx.x == 0)
        atomicAdd(out, partial[0] + partial[1] + partial[2] + partial[3]);
}

__global__ void sqrt_kernel(float* out) { out[0] = sqrtf(out[0]); }

__global__ void zero_kernel(float* t, float* out)
{
    int i = blockIdx.x * 256 + threadIdx.x;
    if (i < NN) t[i] = 0.f;
    if (i == 0) out[0] = 0.f;
}

extern "C" void kernel_launch(void* const* d_in, const int* in_sizes, int n_in,
                              void* d_out, int out_size, void* d_ws, size_t ws_size,
                              hipStream_t stream)
{
    const float* x   = (const float*)d_in[0];
    const float* W1  = (const float*)d_in[1];
    const float* b1  = (const float*)d_in[2];
    const float* W2  = (const float*)d_in[3];
    const float* b2  = (const float*)d_in[4];
    const int*   er  = (const int*)d_in[5];
    const int*   ec  = ((const int*)d_in[5]) + NE;
    const float* ew  = (const float*)d_in[6];
    float* out = (float*)d_out;

    float*    ws    = (float*)d_ws;
    float*    s_buf = ws + S_OFF;
    float*    P     = ws + P_OFF;
    unsigned* cnt   = (unsigned*)(ws + CNT_OFF);
    __bf16*   W1p   = (__bf16*)(ws + W1P_OFF);

    if (ws_size >= WS_NEED) {
        prep_w1_kernel<<<16, 256, 0, stream>>>(W1, W1p, out, cnt);
        stage1_kernel<<<NTILE, 256, 0, stream>>>(x, W1p, b1, W2, s_buf);
        spmv_lds_kernel<<<NR * EC, 1024, 0, stream>>>(er, ec, ew, s_buf, P);
        int fb = (NN + 255) / 256;
        finish_lds_kernel<<<fb, 256, 0, stream>>>(P, b2, out, cnt, fb);
    } else {
        // Dense-atomic fallback (needs ~700 KB of ws)
        float*    t    = ws + P_OFF;
        __bf16*   W1pf = (__bf16*)(ws + P_OFF + NN);
        unsigned* cntf = (unsigned*)(ws + P_OFF + NN + DD * KD / 2);
        prep_w1_kernel<<<16, 256, 0, stream>>>(W1, W1pf, out, cntf);
        zero_kernel<<<(NN + 255) / 256, 256, 0, stream>>>(t, out);
        stage1_kernel<<<NTILE, 256, 0, stream>>>(x, W1pf, b1, W2, s_buf);
        spmv_fallback_kernel<<<(NE / 4 + 255) / 256, 256, 0, stream>>>(er, ec, ew, s_buf, t);
        finish_fallback_kernel<<<(NN + 255) / 256, 256, 0, stream>>>(t, b2, out);
        sqrt_kernel<<<1, 1, 0, stream>>>(out);
    }
}